// Round 2
// baseline (1550.041 us; speedup 1.0000x reference)
//
#include <hip/hip_runtime.h>
#include <cstdint>
#include <cstddef>

typedef unsigned short ushort_t;
typedef __attribute__((ext_vector_type(8))) short short8;
typedef __attribute__((ext_vector_type(4))) float f32x4;

#define MFMA16(a,b,c) __builtin_amdgcn_mfma_f32_16x16x32_bf16((a),(b),(c),0,0,0)

__device__ __forceinline__ float bf2f(ushort_t u){ return __uint_as_float(((unsigned)u)<<16); }
__device__ __forceinline__ ushort_t f2bf(float f){
  unsigned u = __float_as_uint(f);
  u += 0x7fffu + ((u>>16)&1u);      // RNE
  return (ushort_t)(u>>16);
}
// load 8 consecutive f32, convert to 8 bf16 (RNE)
__device__ __forceinline__ short8 ldcvt8(const float* __restrict__ p){
  f32x4 a = *(const f32x4*)(p);
  f32x4 b = *(const f32x4*)(p+4);
  short8 r;
  r[0]=(short)f2bf(a[0]); r[1]=(short)f2bf(a[1]); r[2]=(short)f2bf(a[2]); r[3]=(short)f2bf(a[3]);
  r[4]=(short)f2bf(b[0]); r[5]=(short)f2bf(b[1]); r[6]=(short)f2bf(b[2]); r[7]=(short)f2bf(b[3]);
  return r;
}
__device__ __forceinline__ float sigm(float x){ return 1.f/(1.f+__expf(-x)); }
__device__ __forceinline__ float tanh_f(float x){
  x = fminf(fmaxf(x,-15.f),15.f);
  float e = __expf(2.f*x);
  return (e-1.f)/(e+1.f);
}

// ---------------- grid spin barrier (32 co-resident blocks) ----------------
__device__ __forceinline__ void gridbar(unsigned* bar, int gen, unsigned nblk, int tid){
  __threadfence();
  __syncthreads();
  if (tid == 0){
    __hip_atomic_fetch_add(&bar[gen], 1u, __ATOMIC_ACQ_REL, __HIP_MEMORY_SCOPE_AGENT);
    while (__hip_atomic_load(&bar[gen], __ATOMIC_ACQUIRE, __HIP_MEMORY_SCOPE_AGENT) < nblk){
      __builtin_amdgcn_s_sleep(1);
    }
  }
  __syncthreads();
  __threadfence();
}

// ---------------- init: h0 (f32->bf16), dt publication buffer, barriers ----
__global__ void init_k(const float* __restrict__ enc, ushort_t* __restrict__ hbuf,
                       ushort_t* __restrict__ dtpub, unsigned* __restrict__ bar){
  int i = blockIdx.x*blockDim.x + threadIdx.x;
  int n = gridDim.x*blockDim.x;
  for (int e = i; e < 32*512; e += n) hbuf[e] = f2bf(enc[e]);   // h0 = enc_output
  for (int e = i; e < 32*224; e += n) dtpub[e] = 0;
  for (int e = i; e < 128;    e += n) bar[e] = 0;
}

// ---------------- generic GEMM: C[M,N] = gather(A)[M,K] @ Bw[N,K]^T + bias --
// A either f32 (converted) or bf16 (our scratch). Bw/bias f32. C f32.
// 128x128 tile, BK=32, 256 thr (2x2 waves of 64x64), MFMA 16x16x32 bf16.
template<bool A_F32>
__global__ __launch_bounds__(256) void gemm_bt(
    const void* __restrict__ A_, const int* __restrict__ idx,
    const float* __restrict__ Bw, const float* __restrict__ bias,
    float* __restrict__ C, int M, int N, int K, int ldA)
{
  __shared__ __attribute__((aligned(16))) short As[128*40];
  __shared__ __attribute__((aligned(16))) short Bs[128*40];
  const int tid = threadIdx.x;
  const int wave = tid>>6, lane = tid&63, quad = lane>>4, l16 = lane&15;
  const int wr_ = wave>>1, wc = wave&1;
  const int bm = blockIdx.y, bn = blockIdx.x;

  f32x4 acc[4][4];
  #pragma unroll
  for (int i=0;i<4;++i)
    #pragma unroll
    for (int j=0;j<4;++j) acc[i][j] = f32x4{0.f,0.f,0.f,0.f};

  const int nkt = K >> 5;
  for (int kt = 0; kt < nkt; ++kt){
    __syncthreads();
    // stage A tile (128 x 32): 512 chunks of 8 elements
    for (int c = tid; c < 512; c += 256){
      int row = c>>2, kq = c&3;
      int rowg = bm*128 + row;
      int rowc = rowg < M ? rowg : M-1;
      int src  = idx ? idx[rowc] : rowc;
      short8 v;
      if (A_F32) v = ldcvt8((const float*)A_ + (size_t)src*ldA + kt*32 + kq*8);
      else       v = *(const short8*)((const ushort_t*)A_ + (size_t)src*ldA + kt*32 + kq*8);
      *(short8*)&As[row*40 + kq*8] = v;
    }
    // stage B tile (128 x 32), f32 -> bf16
    for (int c = tid; c < 512; c += 256){
      int row = c>>2, kq = c&3;
      int rowg = bn*128 + row;
      int rowc = rowg < N ? rowg : N-1;
      short8 v = ldcvt8(Bw + (size_t)rowc*K + kt*32 + kq*8);
      *(short8*)&Bs[row*40 + kq*8] = v;
    }
    __syncthreads();
    short8 a[4], b[4];
    #pragma unroll
    for (int i=0;i<4;++i) a[i] = *(const short8*)&As[(wr_*64 + i*16 + l16)*40 + quad*8];
    #pragma unroll
    for (int j=0;j<4;++j) b[j] = *(const short8*)&Bs[(wc*64 + j*16 + l16)*40 + quad*8];
    #pragma unroll
    for (int i=0;i<4;++i)
      #pragma unroll
      for (int j=0;j<4;++j)
        acc[i][j] = MFMA16(a[i], b[j], acc[i][j]);
  }

  // epilogue: D[row=quad*4+r][col=l16] per 16x16 tile
  #pragma unroll
  for (int j=0;j<4;++j){
    int colg = bn*128 + wc*64 + j*16 + l16;
    if (colg >= N) continue;
    float bz = bias[colg];
    #pragma unroll
    for (int i=0;i<4;++i){
      #pragma unroll
      for (int r=0;r<4;++r){
        int rowg = bm*128 + wr_*64 + i*16 + quad*4 + r;
        if (rowg < M) C[(size_t)rowg*N + colg] = acc[i][j][r] + bz;
      }
    }
  }
}

// ---------------- persistent recurrent kernel: 32 blocks, 2 barriers/step --
__global__ __launch_bounds__(256) void sclstm_rec(
    const float* __restrict__ enc,  const float* __restrict__ act,
    const float* __restrict__ Wh2h, const float* __restrict__ bh2h,
    const float* __restrict__ Whr,  const float* __restrict__ bhr,
    const float* __restrict__ Wdc,
    const float* __restrict__ w4all, const float* __restrict__ wrall,
    ushort_t* __restrict__ hbuf, ushort_t* __restrict__ dtpub,
    ushort_t* __restrict__ H, unsigned* __restrict__ bar)
{
  constexpr int T = 55;
  const int tid = threadIdx.x;
  const int wave = tid>>6, lane = tid&63, quad = lane>>4, l16 = lane&15;
  const int blk = blockIdx.x;
  const int j0 = blk*16;            // this block's 16 h/c columns

  __shared__ __attribute__((aligned(16))) short h_lds[32*520];   // h_t
  __shared__ __attribute__((aligned(16))) short wh_lds[64*520];  // W_h2h rows {g*512+j0+i}
  __shared__ __attribute__((aligned(16))) short whr_lds[16*520]; // W_h2h_r rows blk*16..
  __shared__ __attribute__((aligned(16))) short wdc_lds[16*240]; // W_dc rows j0.., K 200->240 zero-pad
  __shared__ float c_lds[32*16];
  __shared__ float U_lds[32*16];
  __shared__ float dt_loc[32*16];   // fp32 dt slice (blocks 0..12)

  // ---- one-time staging (f32 -> bf16) ----
  for (int c = tid; c < 64*64; c += 256){
    int s = c>>6, k8 = (c&63)<<3;
    int g = s>>4, i = s&15;
    *(short8*)&wh_lds[s*520 + k8] = ldcvt8(Wh2h + (size_t)(g*512 + j0 + i)*512 + k8);
  }
  if (blk < 13){
    for (int c = tid; c < 16*64; c += 256){
      int s = c>>6, k8 = (c&63)<<3;
      int row = blk*16 + s;
      short8 v = {0,0,0,0,0,0,0,0};
      if (row < 200) v = ldcvt8(Whr + (size_t)row*512 + k8);
      *(short8*)&whr_lds[s*520 + k8] = v;
    }
  }
  {
    int s = tid & 15;
    for (int j = tid>>4; j < 30; j += 16){
      int k8 = j<<3;
      short8 v = {0,0,0,0,0,0,0,0};
      if (k8 + 8 <= 200) v = ldcvt8(Wdc + (size_t)(j0 + s)*200 + k8);
      *(short8*)&wdc_lds[s*240 + k8] = v;
    }
  }
  for (int e = tid; e < 512; e += 256){
    int b = e>>4, c = e&15;
    c_lds[e] = enc[b*512 + j0 + c];           // c0 = h0
  }
  if (blk < 13){
    for (int e = tid; e < 512; e += 256){
      int b = e>>4, lc = e&15;
      int a = blk*16 + lc;
      dt_loc[e] = (a < 200) ? act[b*200 + a] : 0.f;
    }
  }
  __syncthreads();

  for (int t = 0; t < T; ++t){
    const int par = t & 1;
    const ushort_t* hsrc = hbuf + par*(32*512);
    // stage h_t (bf16 scratch, direct)
    for (int c = tid; c < 2048; c += 256){
      int b = c>>6, k8 = (c&63)<<3;
      *(short8*)&h_lds[b*520 + k8] = *(const short8*)(hsrc + b*512 + k8);
    }
    __syncthreads();

    // ---- phase A: gate GEMM (waves 0,1) + r-path slice (waves 2,3, blk<13)
    f32x4 gacc[4];
    if (wave < 2){
      const int m = wave;
      #pragma unroll
      for (int g=0; g<4; ++g) gacc[g] = f32x4{0.f,0.f,0.f,0.f};
      for (int kt = 0; kt < 16; ++kt){
        short8 af = *(const short8*)&h_lds[(m*16 + l16)*520 + kt*32 + quad*8];
        #pragma unroll
        for (int g = 0; g < 4; ++g){
          short8 bfr = *(const short8*)&wh_lds[(g*16 + l16)*520 + kt*32 + quad*8];
          gacc[g] = MFMA16(af, bfr, gacc[g]);
        }
      }
    } else if (blk < 13){
      const int m = wave - 2;
      f32x4 racc = f32x4{0.f,0.f,0.f,0.f};
      for (int kt = 0; kt < 16; ++kt){
        short8 af  = *(const short8*)&h_lds[(m*16 + l16)*520 + kt*32 + quad*8];
        short8 bfr = *(const short8*)&whr_lds[l16*520 + kt*32 + quad*8];
        racc = MFMA16(af, bfr, racc);
      }
      #pragma unroll
      for (int r = 0; r < 4; ++r){
        int b = m*16 + quad*4 + r;
        int a = blk*16 + l16;
        float dtv = 0.f;
        if (a < 200){
          float rv = racc[r] + wrall[(size_t)(b*T + t)*200 + a] + bhr[a];
          dtv = dt_loc[b*16 + l16] * sigm(rv);
        }
        dt_loc[b*16 + l16] = dtv;
        dtpub[b*224 + a] = f2bf(dtv);     // publish dt_{t+1}
      }
    }
    gridbar(bar, 2*t, 32, tid);

    // ---- phase B: dc GEMM -> U (waves 2,3), then elementwise (waves 0,1)
    if (wave >= 2){
      const int m = wave - 2;
      f32x4 uacc = f32x4{0.f,0.f,0.f,0.f};
      for (int kt = 0; kt < 7; ++kt){
        short8 af  = *(const short8*)(dtpub + (size_t)(m*16 + l16)*224 + kt*32 + quad*8);
        short8 bfr = *(const short8*)&wdc_lds[l16*240 + kt*32 + quad*8];
        uacc = MFMA16(af, bfr, uacc);
      }
      #pragma unroll
      for (int r = 0; r < 4; ++r){
        int b = m*16 + quad*4 + r;
        U_lds[b*16 + l16] = tanh_f(uacc[r]);
      }
    }
    __syncthreads();
    if (wave < 2){
      const int m = wave;
      ushort_t* hdst = hbuf + (1-par)*(32*512);
      #pragma unroll
      for (int r = 0; r < 4; ++r){
        int b = m*16 + quad*4 + r;
        int j = j0 + l16;
        size_t rowb = (size_t)(b*T + t);
        float g0 = gacc[0][r] + w4all[rowb*2048 +        j] + bh2h[       j];
        float g1 = gacc[1][r] + w4all[rowb*2048 +  512 + j] + bh2h[ 512 + j];
        float g2 = gacc[2][r] + w4all[rowb*2048 + 1024 + j] + bh2h[1024 + j];
        float g3 = gacc[3][r] + w4all[rowb*2048 + 1536 + j] + bh2h[1536 + j];
        float gi = sigm(g0), gf = sigm(g1), go = sigm(g2), ch = tanh_f(g3);
        float cc = c_lds[b*16 + l16];
        cc = gf*cc + gi*ch + U_lds[b*16 + l16];
        c_lds[b*16 + l16] = cc;
        ushort_t hb = f2bf(go * tanh_f(cc));
        hdst[b*512 + j] = hb;             // h_{t+1} for next step
        H[rowb*512 + j] = hb;             // row (b*T+t) feeds output GEMM
      }
    }
    if (t < T-1) gridbar(bar, 2*t+1, 32, tid);
  }
}

// ---------------------------------------------------------------------------
extern "C" void kernel_launch(void* const* d_in, const int* in_sizes, int n_in,
                              void* d_out, int out_size, void* d_ws, size_t ws_size,
                              hipStream_t stream)
{
  const int*   tgt  = (const int*)d_in[0];
  const float* enc  = (const float*)d_in[1];
  const float* act  = (const float*)d_in[2];
  const float* E    = (const float*)d_in[3];
  const float* Ww2h = (const float*)d_in[4];
  const float* bw2h = (const float*)d_in[5];
  const float* Wh2h = (const float*)d_in[6];
  const float* bh2h = (const float*)d_in[7];
  const float* Wwr  = (const float*)d_in[8];
  const float* bwr  = (const float*)d_in[9];
  const float* Whr  = (const float*)d_in[10];
  const float* bhr  = (const float*)d_in[11];
  const float* Wdc  = (const float*)d_in[12];
  const float* Wout = (const float*)d_in[13];
  const float* bout = (const float*)d_in[14];
  float* out = (float*)d_out;

  char* ws = (char*)d_ws;
  unsigned* bar   = (unsigned*)(ws);                      // 512 B used
  ushort_t* dtpub = (ushort_t*)(ws + 4096);               // 32*224*2      = 14,336
  ushort_t* hbuf  = (ushort_t*)(ws + 32768);              // 2*32*512*2    = 65,536
  float*    w4all = (float*)(ws + 98304);                 // 1760*2048*4   = 14,417,920
  float*    wrall = (float*)(ws + 98304 + 14417920);      // 1760*200*4    = 1,408,000
  ushort_t* Hm    = (ushort_t*)(ws + 98304 + 14417920 + 1408000); // 1760*512*2

  init_k<<<32, 256, 0, stream>>>(enc, hbuf, dtpub, bar);
  // w4_all = gather(E, tgt) @ W_w2h^T + b  (M=1760, N=2048, K=256)
  gemm_bt<true><<<dim3(16,14), 256, 0, stream>>>(E, tgt, Ww2h, bw2h, w4all, 1760, 2048, 256, 256);
  // wr_all = gather(E, tgt) @ W_w2h_r^T + b (N=200)
  gemm_bt<true><<<dim3(2,14), 256, 0, stream>>>(E, tgt, Wwr, bwr, wrall, 1760, 200, 256, 256);
  // 55-step recurrence (persistent, 32 blocks)
  sclstm_rec<<<32, 256, 0, stream>>>(enc, act, Wh2h, bh2h, Whr, bhr, Wdc,
                                     w4all, wrall, hbuf, dtpub, Hm, bar);
  // out = H @ W_out^T + b_out  (M=1760, N=32000, K=512)
  gemm_bt<false><<<dim3(250,14), 256, 0, stream>>>(Hm, nullptr, Wout, bout, out, 1760, 32000, 512, 512);
}

// Round 3
// 1172.359 us; speedup vs baseline: 1.3222x; 1.3222x over previous
//
#include <hip/hip_runtime.h>
#include <cstdint>
#include <cstddef>

typedef unsigned short ushort_t;
typedef unsigned int uint32;
typedef unsigned long long u64;
typedef __attribute__((ext_vector_type(8))) short short8;
typedef __attribute__((ext_vector_type(4))) float f32x4;

#define MFMA16(a,b,c) __builtin_amdgcn_mfma_f32_16x16x32_bf16((a),(b),(c),0,0,0)

union Pack16 { short8 s8; u64 q[2]; uint32 d[4]; };

__device__ __forceinline__ ushort_t f2bf(float f){
  unsigned u = __float_as_uint(f);
  u += 0x7fffu + ((u>>16)&1u);      // RNE
  return (ushort_t)(u>>16);
}
__device__ __forceinline__ short8 ldcvt8(const float* __restrict__ p){
  f32x4 a = *(const f32x4*)(p);
  f32x4 b = *(const f32x4*)(p+4);
  short8 r;
  r[0]=(short)f2bf(a[0]); r[1]=(short)f2bf(a[1]); r[2]=(short)f2bf(a[2]); r[3]=(short)f2bf(a[3]);
  r[4]=(short)f2bf(b[0]); r[5]=(short)f2bf(b[1]); r[6]=(short)f2bf(b[2]); r[7]=(short)f2bf(b[3]);
  return r;
}
__device__ __forceinline__ float sigm(float x){ return 1.f/(1.f+__expf(-x)); }
__device__ __forceinline__ float tanh_f(float x){
  x = fminf(fmaxf(x,-15.f),15.f);
  float e = __expf(2.f*x);
  return (e-1.f)/(e+1.f);
}

// ---- coherent (agent-scope, relaxed) accessors: sc0|sc1, NO cache flushes --
__device__ __forceinline__ void st_coh_u32(uint32* p, uint32 v){
  __hip_atomic_store(p, v, __ATOMIC_RELAXED, __HIP_MEMORY_SCOPE_AGENT);
}
__device__ __forceinline__ u64 ld_coh_u64(const u64* p){
  return __hip_atomic_load(p, __ATOMIC_RELAXED, __HIP_MEMORY_SCOPE_AGENT);
}
__device__ __forceinline__ short8 ld_coh_8bf(const uint32* p /*16B aligned*/){
  Pack16 pk;
  pk.q[0] = ld_coh_u64((const u64*)p);
  pk.q[1] = ld_coh_u64((const u64*)p + 1);
  return pk.s8;
}

// ---- grid barrier: drain own stores, relaxed arrive, relaxed spin ---------
__device__ __forceinline__ void barsync(unsigned* bar, int gen, unsigned target,
                                        bool arrive, int tid){
  asm volatile("s_waitcnt vmcnt(0)" ::: "memory");   // own sc-stores complete
  __syncthreads();                                   // all waves drained
  if (tid == 0){
    if (arrive)
      __hip_atomic_fetch_add(&bar[gen], 1u, __ATOMIC_RELAXED, __HIP_MEMORY_SCOPE_AGENT);
    while (__hip_atomic_load(&bar[gen], __ATOMIC_RELAXED, __HIP_MEMORY_SCOPE_AGENT) < target)
      __builtin_amdgcn_s_sleep(1);
  }
  __syncthreads();
}

// ---- init: h0 packed bf16 pairs, dt pub buffer, barrier counters ----------
__global__ void init_k(const float* __restrict__ enc, uint32* __restrict__ hpub,
                       uint32* __restrict__ dtpub, unsigned* __restrict__ bar){
  int i = blockIdx.x*blockDim.x + threadIdx.x;
  int n = gridDim.x*blockDim.x;
  for (int e = i; e < 32*256; e += n){
    int b = e>>8, jp = e&255;
    uint32 lo = f2bf(enc[b*512 + jp*2]);
    uint32 hi = f2bf(enc[b*512 + jp*2 + 1]);
    hpub[e] = lo | (hi<<16);
  }
  for (int e = i; e < 32*112; e += n) dtpub[e] = 0;
  for (int e = i; e < 128;    e += n) bar[e] = 0;
}

// ---------------- generic GEMM: C[M,N] = gather(A)[M,K] @ Bw[N,K]^T + bias(+bias2)
template<bool A_F32>
__global__ __launch_bounds__(256) void gemm_bt(
    const void* __restrict__ A_, const int* __restrict__ idx,
    const float* __restrict__ Bw, const float* __restrict__ bias,
    const float* __restrict__ bias2,
    float* __restrict__ C, int M, int N, int K, int ldA)
{
  __shared__ __attribute__((aligned(16))) short As[128*40];
  __shared__ __attribute__((aligned(16))) short Bs[128*40];
  const int tid = threadIdx.x;
  const int wave = tid>>6, lane = tid&63, quad = lane>>4, l16 = lane&15;
  const int wr_ = wave>>1, wc = wave&1;
  const int bm = blockIdx.y, bn = blockIdx.x;

  f32x4 acc[4][4];
  #pragma unroll
  for (int i=0;i<4;++i)
    #pragma unroll
    for (int j=0;j<4;++j) acc[i][j] = f32x4{0.f,0.f,0.f,0.f};

  const int nkt = K >> 5;
  for (int kt = 0; kt < nkt; ++kt){
    __syncthreads();
    for (int c = tid; c < 512; c += 256){
      int row = c>>2, kq = c&3;
      int rowg = bm*128 + row;
      int rowc = rowg < M ? rowg : M-1;
      int src  = idx ? idx[rowc] : rowc;
      short8 v;
      if (A_F32) v = ldcvt8((const float*)A_ + (size_t)src*ldA + kt*32 + kq*8);
      else       v = *(const short8*)((const ushort_t*)A_ + (size_t)src*ldA + kt*32 + kq*8);
      *(short8*)&As[row*40 + kq*8] = v;
    }
    for (int c = tid; c < 512; c += 256){
      int row = c>>2, kq = c&3;
      int rowg = bn*128 + row;
      int rowc = rowg < N ? rowg : N-1;
      short8 v = ldcvt8(Bw + (size_t)rowc*K + kt*32 + kq*8);
      *(short8*)&Bs[row*40 + kq*8] = v;
    }
    __syncthreads();
    short8 a[4], b[4];
    #pragma unroll
    for (int i=0;i<4;++i) a[i] = *(const short8*)&As[(wr_*64 + i*16 + l16)*40 + quad*8];
    #pragma unroll
    for (int j=0;j<4;++j) b[j] = *(const short8*)&Bs[(wc*64 + j*16 + l16)*40 + quad*8];
    #pragma unroll
    for (int i=0;i<4;++i)
      #pragma unroll
      for (int j=0;j<4;++j)
        acc[i][j] = MFMA16(a[i], b[j], acc[i][j]);
  }

  #pragma unroll
  for (int j=0;j<4;++j){
    int colg = bn*128 + wc*64 + j*16 + l16;
    if (colg >= N) continue;
    float bz = bias[colg] + (bias2 ? bias2[colg] : 0.f);
    #pragma unroll
    for (int i=0;i<4;++i){
      #pragma unroll
      for (int r=0;r<4;++r){
        int rowg = bm*128 + wr_*64 + i*16 + quad*4 + r;
        if (rowg < M) C[(size_t)rowg*N + colg] = acc[i][j][r] + bz;
      }
    }
  }
}

// ---------------- persistent recurrent kernel: 32 blocks ------------------
// Cross-block data (h, dt) exchanged via agent-scope relaxed atomics (IF$-
// coherent, no L2 flushes). 2 light barriers/step.
__global__ __launch_bounds__(256) void sclstm_rec(
    const float* __restrict__ enc,  const float* __restrict__ act,
    const float* __restrict__ Wh2h, const float* __restrict__ Whr,
    const float* __restrict__ Wdc,
    const float* __restrict__ w4all, const float* __restrict__ wrall,
    uint32* __restrict__ hpub,      // 2 × [32 rows × 256 u32] packed bf16 pairs
    uint32* __restrict__ dtpub,     // [32 rows × 112 u32] packed bf16 pairs
    uint32* __restrict__ H32,       // [1760 rows × 256 u32] bf16-pair H matrix
    unsigned* __restrict__ bar)
{
  constexpr int T = 55;
  const int tid = threadIdx.x;
  const int wave = tid>>6, lane = tid&63, quad = lane>>4, l16 = lane&15;
  const int blk = blockIdx.x;
  const int j0 = blk*16;            // this block's 16 h/c columns

  __shared__ __attribute__((aligned(16))) short wh_lds[64*520];  // W_h2h rows {g*512+j0+i}
  __shared__ __attribute__((aligned(16))) short whr_lds[16*520]; // W_h2h_r rows blk*16..
  __shared__ __attribute__((aligned(16))) short wdc_lds[16*240]; // W_dc rows j0.., K 200->240 zero-pad
  __shared__ float c_lds[32*16];
  __shared__ float U_lds[32*16];
  __shared__ float dt_loc[32*16];   // fp32 dt slice (blocks 0..12)

  // ---- one-time staging (f32 -> bf16) ----
  for (int c = tid; c < 64*64; c += 256){
    int s = c>>6, k8 = (c&63)<<3;
    int g = s>>4, i = s&15;
    *(short8*)&wh_lds[s*520 + k8] = ldcvt8(Wh2h + (size_t)(g*512 + j0 + i)*512 + k8);
  }
  if (blk < 13){
    for (int c = tid; c < 16*64; c += 256){
      int s = c>>6, k8 = (c&63)<<3;
      int row = blk*16 + s;
      short8 v = {0,0,0,0,0,0,0,0};
      if (row < 200) v = ldcvt8(Whr + (size_t)row*512 + k8);
      *(short8*)&whr_lds[s*520 + k8] = v;
    }
  }
  {
    int s = tid & 15;
    for (int j = tid>>4; j < 30; j += 16){
      int k8 = j<<3;
      short8 v = {0,0,0,0,0,0,0,0};
      if (k8 + 8 <= 200) v = ldcvt8(Wdc + (size_t)(j0 + s)*200 + k8);
      *(short8*)&wdc_lds[s*240 + k8] = v;
    }
  }
  for (int e = tid; e < 512; e += 256){
    int b = e>>4, c = e&15;
    c_lds[e] = enc[b*512 + j0 + c];           // c0 = h0
  }
  if (blk < 13){
    for (int e = tid; e < 512; e += 256){
      int b = e>>4, lc = e&15;
      int a = blk*16 + lc;
      dt_loc[e] = (a < 200) ? act[b*200 + a] : 0.f;
    }
  }
  __syncthreads();

  for (int t = 0; t < T; ++t){
    const uint32* hsrc = hpub + (t&1)*(32*256);
    uint32*       hdst = hpub + ((t+1)&1)*(32*256);

    // ---- phase A ----
    f32x4 gacc[4];
    float w4v[4][4];
    if (wave < 2){
      const int row = wave*16 + l16;          // batch row this lane loads
      #pragma unroll
      for (int g=0; g<4; ++g) gacc[g] = f32x4{0.f,0.f,0.f,0.f};
      #pragma unroll
      for (int kt = 0; kt < 16; ++kt){
        short8 af = ld_coh_8bf(hsrc + row*256 + kt*16 + quad*4);
        #pragma unroll
        for (int g = 0; g < 4; ++g){
          short8 bfr = *(const short8*)&wh_lds[(g*16 + l16)*520 + kt*32 + quad*8];
          gacc[g] = MFMA16(af, bfr, gacc[g]);
        }
      }
      // prefetch this step's w4all slice into registers (hides latency behind barrier)
      #pragma unroll
      for (int r = 0; r < 4; ++r){
        int b = wave*16 + quad*4 + r;
        size_t rowb = (size_t)(b*T + t);
        #pragma unroll
        for (int g = 0; g < 4; ++g)
          w4v[g][r] = w4all[rowb*2048 + g*512 + j0 + l16];
      }
    } else if (blk < 13){
      const int row = (wave-2)*16 + l16;
      f32x4 racc = f32x4{0.f,0.f,0.f,0.f};
      #pragma unroll
      for (int kt = 0; kt < 16; ++kt){
        short8 af  = ld_coh_8bf(hsrc + row*256 + kt*16 + quad*4);
        short8 bfr = *(const short8*)&whr_lds[l16*520 + kt*32 + quad*8];
        racc = MFMA16(af, bfr, racc);
      }
      #pragma unroll
      for (int r = 0; r < 4; ++r){
        int b = (wave-2)*16 + quad*4 + r;
        int a = blk*16 + l16;
        float dtv = 0.f;
        if (a < 200){
          float rv = racc[r] + wrall[(size_t)(b*T + t)*200 + a];  // bhr folded in
          dtv = dt_loc[b*16 + l16] * sigm(rv);
        }
        dt_loc[b*16 + l16] = dtv;
        unsigned v = f2bf(dtv);
        unsigned o = __shfl_down(v, 1);
        if (!(l16 & 1))
          st_coh_u32(&dtpub[b*112 + blk*8 + (l16>>1)], v | (o<<16));
      }
    }
    barsync(bar, 2*t, 13, blk < 13, tid);   // dt published by 13 producer blocks

    // ---- phase B: dc GEMM -> U (waves 2,3) ----
    if (wave >= 2){
      const int m = wave - 2;
      f32x4 uacc = f32x4{0.f,0.f,0.f,0.f};
      #pragma unroll
      for (int kt = 0; kt < 7; ++kt){
        short8 af  = ld_coh_8bf(dtpub + (m*16 + l16)*112 + kt*16 + quad*4);
        short8 bfr = *(const short8*)&wdc_lds[l16*240 + kt*32 + quad*8];
        uacc = MFMA16(af, bfr, uacc);
      }
      #pragma unroll
      for (int r = 0; r < 4; ++r){
        int b = m*16 + quad*4 + r;
        U_lds[b*16 + l16] = tanh_f(uacc[r]);
      }
    }
    __syncthreads();

    // ---- elementwise + publish h (waves 0,1) ----
    if (wave < 2){
      #pragma unroll
      for (int r = 0; r < 4; ++r){
        int b = wave*16 + quad*4 + r;
        int j = j0 + l16;
        size_t rowb = (size_t)(b*T + t);
        float gi = sigm(gacc[0][r] + w4v[0][r]);   // bh2h folded into w4all
        float gf = sigm(gacc[1][r] + w4v[1][r]);
        float go = sigm(gacc[2][r] + w4v[2][r]);
        float ch = tanh_f(gacc[3][r] + w4v[3][r]);
        float cc = c_lds[b*16 + l16];
        cc = gf*cc + gi*ch + U_lds[b*16 + l16];
        c_lds[b*16 + l16] = cc;
        unsigned v = f2bf(go * tanh_f(cc));
        unsigned o = __shfl_down(v, 1);
        if (!(l16 & 1)){
          uint32 pk = v | (o<<16);
          st_coh_u32(&hdst[b*256 + blk*8 + (l16>>1)], pk);   // h_{t+1}
          H32[rowb*256 + blk*8 + (l16>>1)] = pk;             // feeds output GEMM
        }
      }
    }
    if (t < T-1) barsync(bar, 2*t+1, 32, true, tid);
  }
}

// ---------------------------------------------------------------------------
extern "C" void kernel_launch(void* const* d_in, const int* in_sizes, int n_in,
                              void* d_out, int out_size, void* d_ws, size_t ws_size,
                              hipStream_t stream)
{
  const int*   tgt  = (const int*)d_in[0];
  const float* enc  = (const float*)d_in[1];
  const float* act  = (const float*)d_in[2];
  const float* E    = (const float*)d_in[3];
  const float* Ww2h = (const float*)d_in[4];
  const float* bw2h = (const float*)d_in[5];
  const float* Wh2h = (const float*)d_in[6];
  const float* bh2h = (const float*)d_in[7];
  const float* Wwr  = (const float*)d_in[8];
  const float* bwr  = (const float*)d_in[9];
  const float* Whr  = (const float*)d_in[10];
  const float* bhr  = (const float*)d_in[11];
  const float* Wdc  = (const float*)d_in[12];
  const float* Wout = (const float*)d_in[13];
  const float* bout = (const float*)d_in[14];
  float* out = (float*)d_out;

  char* ws = (char*)d_ws;
  unsigned* bar   = (unsigned*)(ws);                      // 512 B used
  uint32*   dtpub = (uint32*)(ws + 4096);                 // 32*112*4  = 14,336
  uint32*   hpub  = (uint32*)(ws + 32768);                // 2*32*256*4= 65,536
  float*    w4all = (float*)(ws + 98304);                 // 1760*2048*4 = 14,417,920
  float*    wrall = (float*)(ws + 98304 + 14417920);      // 1760*200*4  = 1,408,000
  uint32*   Hm32  = (uint32*)(ws + 98304 + 14417920 + 1408000); // 1760*256*4 (bf16 pairs)

  init_k<<<32, 256, 0, stream>>>(enc, hpub, dtpub, bar);
  // w4_all = gather(E, tgt) @ W_w2h^T + (b_w2h + b_h2h)
  gemm_bt<true><<<dim3(16,14), 256, 0, stream>>>(E, tgt, Ww2h, bw2h, bh2h, w4all, 1760, 2048, 256, 256);
  // wr_all = gather(E, tgt) @ W_w2h_r^T + (b_w2h_r + b_h2h_r)
  gemm_bt<true><<<dim3(2,14), 256, 0, stream>>>(E, tgt, Wwr, bwr, bhr, wrall, 1760, 200, 256, 256);
  // 55-step recurrence (persistent, 32 blocks)
  sclstm_rec<<<32, 256, 0, stream>>>(enc, act, Wh2h, Whr, Wdc,
                                     w4all, wrall, hpub, dtpub, Hm32, bar);
  // out = H @ W_out^T + b_out  (M=1760, N=32000, K=512)
  gemm_bt<false><<<dim3(250,14), 256, 0, stream>>>(Hm32, nullptr, Wout, bout, nullptr, out, 1760, 32000, 512, 512);
}